// Round 18
// baseline (901.737 us; speedup 1.0000x reference)
//
#include <hip/hip_runtime.h>
#include <stdint.h>

typedef float f32x4 __attribute__((ext_vector_type(4)));
typedef int i32x4 __attribute__((ext_vector_type(4)));

#define LOG2E 1.4426950408889634f

__device__ __forceinline__ float bf2f(unsigned short u) {
  union { unsigned int i; float f; } x; x.i = ((unsigned int)u) << 16; return x.f;
}
__device__ __forceinline__ float bfu_lo(unsigned u) {
  union { unsigned int i; float f; } x; x.i = u << 16; return x.f;
}
__device__ __forceinline__ float bfu_hi(unsigned u) {
  union { unsigned int i; float f; } x; x.i = u & 0xffff0000u; return x.f;
}
__device__ __forceinline__ unsigned short f2bf(float f) {
  union { float f; unsigned int i; } x; x.f = f;
  unsigned int u = x.i + 0x7fffu + ((x.i >> 16) & 1u);
  return (unsigned short)(u >> 16);
}
__device__ __forceinline__ float fexp2(float x) {
#if __has_builtin(__builtin_amdgcn_exp2f)
  return __builtin_amdgcn_exp2f(x);
#else
  return exp2f(x);
#endif
}
__device__ __forceinline__ float frcp(float x) {
#if __has_builtin(__builtin_amdgcn_rcpf)
  return __builtin_amdgcn_rcpf(x);
#else
  return 1.f / x;
#endif
}
__device__ __forceinline__ float fast_exp(float x) { return fexp2(x * LOG2E); }
__device__ __forceinline__ float fast_tanh(float x) {
  float e = fexp2(x * (2.f * LOG2E));
  return 1.f - 2.f * frcp(e + 1.f);
}
__device__ __forceinline__ float fast_sigmoid(float x) {
  return frcp(1.f + fexp2(-x * LOG2E));
}

__device__ __forceinline__ void mfma_bf16_16x16x32(f32x4& d, i32x4 a, i32x4 b) {
  asm("v_mfma_f32_16x16x32_bf16 %0, %1, %2, %0" : "+v"(d) : "v"(a), "v"(b));
}

__device__ __forceinline__ void stage16(const unsigned short* g, unsigned short* lds_wave_base, int lane) {
#if __has_builtin(__builtin_amdgcn_global_load_lds)
  __builtin_amdgcn_global_load_lds(
      (const __attribute__((address_space(1))) unsigned int*)(uintptr_t)g,
      (__attribute__((address_space(3))) unsigned int*)(uintptr_t)lds_wave_base,
      16, 0, 0);
#else
  i32x4 v = *(const i32x4*)g;
  *(i32x4*)(lds_wave_base + lane * 8) = v;
#endif
}

// General bijective XCD-aware swizzle (m204 form; valid for any nwg)
__device__ __forceinline__ void xcd_swizzle(int& bx, int& by) {
  int nx = gridDim.x, nwg = nx * gridDim.y;
  int id = by * nx + bx;
  int q = nwg >> 3, r = nwg & 7;
  int x = id & 7, j = id >> 3;
  int swz = (x < r ? x * (q + 1) : r * (q + 1) + (x - r) * q) + j;
  bx = swz % nx;
  by = swz / nx;
}

// ---------------- LDS-staged GEMM (BK=64, XOR-swizzled; R12-proven) ----------------
#define BM 128
#define BN 128
#define BK 64

template <bool OUT_BF16, bool BIAS>
__device__ __forceinline__ void gemm_body(
    const unsigned short* __restrict__ A, const unsigned short* __restrict__ B,
    void* __restrict__ Cout, const float* __restrict__ bias,
    int K, int ldc, int nbound, int m0, int n0)
{
  __shared__ __align__(16) unsigned short lA[BM * BK];
  __shared__ __align__(16) unsigned short lB[BN * BK];
  const int tid = threadIdx.x;
  const int lane = tid & 63;
  const int w = tid >> 6;
  const int wm = w >> 1, wn = w & 1;
  const int fr = lane & 15;
  const int kg = lane >> 4;

  f32x4 acc[4][4];
#pragma unroll
  for (int i = 0; i < 4; ++i)
#pragma unroll
    for (int j = 0; j < 4; ++j) acc[i][j] = 0.f;

  const int nK = K / BK;
  for (int kt = 0; kt < nK; ++kt) {
    const int kb = kt * BK;
#pragma unroll
    for (int i = 0; i < 4; ++i) {
      int c = tid + i * 256;
      int row = c >> 3, k8 = c & 7;
      int sk8 = k8 ^ (row & 7);
      stage16(A + (size_t)(m0 + row) * K + kb + sk8 * 8, lA + (i * 256 + w * 64) * 8, lane);
      stage16(B + (size_t)(n0 + row) * K + kb + sk8 * 8, lB + (i * 256 + w * 64) * 8, lane);
    }
    __syncthreads();

#pragma unroll
    for (int ks = 0; ks < 2; ++ks) {
      const int kc = ks * 4 + kg;
      i32x4 af[4], bfr[4];
#pragma unroll
      for (int i = 0; i < 4; ++i) {
        int ra = wm * 64 + i * 16 + fr;
        af[i] = *(const i32x4*)&lA[ra * 64 + (kc ^ (ra & 7)) * 8];
        int rb = wn * 64 + i * 16 + fr;
        bfr[i] = *(const i32x4*)&lB[rb * 64 + (kc ^ (rb & 7)) * 8];
      }
#pragma unroll
      for (int i = 0; i < 4; ++i)
#pragma unroll
        for (int j = 0; j < 4; ++j) mfma_bf16_16x16x32(acc[i][j], af[i], bfr[j]);
    }
    __syncthreads();
  }

  const int crow = (lane >> 4) * 4;
  const int ccol = lane & 15;
#pragma unroll
  for (int i = 0; i < 4; ++i) {
#pragma unroll
    for (int j = 0; j < 4; ++j) {
      int gn = n0 + wn * 64 + j * 16 + ccol;
      if (gn < nbound) {
        float bv = BIAS ? bias[gn] : 0.f;
        int gmb = m0 + wm * 64 + i * 16 + crow;
#pragma unroll
        for (int r = 0; r < 4; ++r) {
          float v = acc[i][j][r] + bv;
          if (OUT_BF16) ((unsigned short*)Cout)[(size_t)(gmb + r) * ldc + gn] = f2bf(v);
          else          ((float*)Cout)[(size_t)(gmb + r) * ldc + gn] = v;
        }
      }
    }
  }
}

__global__ __launch_bounds__(256) void gemm_bf16out_kernel(
    const unsigned short* __restrict__ A, const unsigned short* __restrict__ B,
    unsigned short* __restrict__ C, int K, int ldc) {
  int bx = blockIdx.x, by = blockIdx.y;
  xcd_swizzle(bx, by);
  gemm_body<true, false>(A, B, C, nullptr, K, ldc, 1 << 30, by * BM, bx * BN);
}
__global__ __launch_bounds__(256) void gemm_f32bias_kernel(
    const unsigned short* __restrict__ A, const unsigned short* __restrict__ B,
    float* __restrict__ C, const float* __restrict__ bias, int K, int ldc, int nbound) {
  int bx = blockIdx.x, by = blockIdx.y;
  xcd_swizzle(bx, by);
  gemm_body<false, true>(A, B, C, bias, K, ldc, nbound, by * BM, bx * BN);
}

// ---------------- merged prep kernel (block-range dispatch; R12-proven) ----------------
__global__ __launch_bounds__(256) void prep_kernel(
    const float* __restrict__ inputs, const float* __restrict__ i2h_w,
    const float* __restrict__ h2h_w, const float* __restrict__ gru_whh,
    const float* __restrict__ gru_wih, const float* __restrict__ gen_w,
    unsigned short* __restrict__ inputs_bf, unsigned short* __restrict__ i2h_bf,
    unsigned short* __restrict__ h2hP, unsigned short* __restrict__ whh_bf,
    unsigned short* __restrict__ wihc_bf, unsigned short* __restrict__ genw_bf,
    unsigned short* __restrict__ ohT_bf)
{
  __shared__ float tile[32][33];
  const int blk = blockIdx.x;
  const int t = threadIdx.x;

  if (blk < 10240) {
    int i = blk * 256 + t;
    float4 v = ((const float4*)inputs)[i];
    ushort4 o; o.x = f2bf(v.x); o.y = f2bf(v.y); o.z = f2bf(v.z); o.w = f2bf(v.w);
    ((ushort4*)inputs_bf)[i] = o;
  } else if (blk < 10496) {
    int i = (blk - 10240) * 256 + t;
    float4 v = ((const float4*)i2h_w)[i];
    ushort4 o; o.x = f2bf(v.x); o.y = f2bf(v.y); o.z = f2bf(v.z); o.w = f2bf(v.w);
    ((ushort4*)i2h_bf)[i] = o;
  } else if (blk < 11520) {
    int i = (blk - 10496) * 256 + t;            // h2hP[kb][row][kk] = h2h_w[row][kb*8+kk]
    int row = i >> 9, c = i & 511;
    int kb = c >> 3, kk = c & 7;
    h2hP[((size_t)kb * 512 + row) * 8 + kk] = f2bf(h2h_w[i]);
  } else if (blk < 12288) {
    int i = (blk - 11520) * 256 + t;
    float4 v = ((const float4*)gru_whh)[i];
    ushort4 o; o.x = f2bf(v.x); o.y = f2bf(v.y); o.z = f2bf(v.z); o.w = f2bf(v.w);
    ((ushort4*)whh_bf)[i] = o;
  } else if (blk < 15360) {
    int i = (blk - 12288) * 256 + t;            // wihc = gru_wih[:, :512]
    int j = i >> 9, c = i & 511;
    wihc_bf[i] = f2bf(gru_wih[(size_t)j * 7137 + c]);
  } else if (blk < 28672) {
    int i = (blk - 15360) * 256 + t;            // genw padded [6656,512]
    int nrow = i >> 9, c = i & 511;
    float v = (nrow < 6625) ? gen_w[(size_t)nrow * 512 + c] : 0.f;
    genw_bf[i] = f2bf(v);
  } else {
    int tb = blk - 28672;                       // ohT[t,j] = gru_wih[j, 512+t]
    int t0 = (tb % 208) * 32;
    int j0 = (tb / 208) * 32;
    int c = t & 31;
    int r4 = t >> 5;
#pragma unroll
    for (int rr = 0; rr < 4; ++rr) {
      int r = r4 + rr * 8;
      int tcol = t0 + c;
      tile[r][c] = (tcol < 6625) ? gru_wih[(size_t)(j0 + r) * 7137 + 512 + tcol] : 0.f;
    }
    __syncthreads();
#pragma unroll
    for (int rr = 0; rr < 4; ++rr) {
      int r = r4 + rr * 8;
      int trow = t0 + r;
      if (trow < 6625) ohT_bf[(size_t)trow * 1536 + j0 + c] = f2bf(tile[c][r]);
    }
  }
}

// ---------------- D1: pp (per-thread dot, packed weights) + attention + vectorized ctx ----------------
__global__ __launch_bounds__(512) void attn_step_kernel(
    const unsigned short* __restrict__ proj_bf,   // [20480, 512]
    const unsigned short* __restrict__ inputs_bf, // [20480, 512]
    const unsigned short* __restrict__ h2hP,      // [64][512][8] packed
    const float* __restrict__ h2h_b,              // [512]
    const float* __restrict__ score_w,            // [512]
    const unsigned short* __restrict__ h_in,      // [256, 512] (ignored when s==0)
    unsigned short* __restrict__ ctx_bf,          // [256, 512]
    int s)
{
  __shared__ float h_lds[512];
  __shared__ float pp_lds[512];
  __shared__ float e_s[80];
  __shared__ float alpha_s[80];
  __shared__ float red[8 * 512];                  // 16KB: per-wave ctx partials

  const int tid = threadIdx.x;
  const int lane = tid & 63;
  const int w = tid >> 6;
  const int b = blockIdx.x;

  if (s > 0) h_lds[tid] = bf2f(h_in[b * 512 + tid]);
  __syncthreads();

  float pacc = h2h_b[tid];
  if (s > 0) {
    const unsigned short* wp = h2hP + (size_t)tid * 8;
#pragma unroll 4
    for (int kb = 0; kb < 64; ++kb) {
      union { i32x4 v; unsigned int u[4]; } wu;
      wu.v = *(const i32x4*)(wp + (size_t)kb * 4096);
#pragma unroll
      for (int q = 0; q < 4; ++q) {
        pacc = fmaf(bfu_lo(wu.u[q]), h_lds[kb * 8 + 2 * q], pacc);
        pacc = fmaf(bfu_hi(wu.u[q]), h_lds[kb * 8 + 2 * q + 1], pacc);
      }
    }
  }
  pp_lds[tid] = pacc;
  __syncthreads();

  // scores
  float ppv[8], swv[8];
#pragma unroll
  for (int j = 0; j < 8; ++j) ppv[j] = pp_lds[lane * 8 + j];
  *(float4*)&swv[0] = *(const float4*)(score_w + lane * 8);
  *(float4*)&swv[4] = *(const float4*)(score_w + lane * 8 + 4);

  for (int t = w; t < 80; t += 8) {
    union { i32x4 v; unsigned int u[4]; } u;
    u.v = *(const i32x4*)(proj_bf + (size_t)(b * 80 + t) * 512 + lane * 8);
    float acc = 0.f;
#pragma unroll
    for (int q = 0; q < 4; ++q) {
      acc += fast_tanh(bfu_lo(u.u[q]) + ppv[2 * q]) * swv[2 * q];
      acc += fast_tanh(bfu_hi(u.u[q]) + ppv[2 * q + 1]) * swv[2 * q + 1];
    }
#pragma unroll
    for (int m = 32; m >= 1; m >>= 1) acc += __shfl_xor(acc, m, 64);
    if (lane == 0) e_s[t] = acc;
  }
  __syncthreads();
  if (w == 0) {
    float v0 = e_s[lane];
    float v1 = (lane < 16) ? e_s[64 + lane] : -1e30f;
    float mx = fmaxf(v0, v1);
#pragma unroll
    for (int m = 32; m >= 1; m >>= 1) mx = fmaxf(mx, __shfl_xor(mx, m, 64));
    float a0 = fast_exp(v0 - mx);
    float a1 = (lane < 16) ? fast_exp(v1 - mx) : 0.f;
    float sm = a0 + a1;
#pragma unroll
    for (int m = 32; m >= 1; m >>= 1) sm += __shfl_xor(sm, m, 64);
    float inv = frcp(sm);
    alpha_s[lane] = a0 * inv;
    if (lane < 16) alpha_s[64 + lane] = a1 * inv;
  }
  __syncthreads();

  // ctx (vectorized, G13): wave w covers ALL 512 channels (8/lane, 16B loads) for its
  // 10 t-values; cross-wave reduction through LDS.
  {
    float c0 = 0.f, c1 = 0.f, c2 = 0.f, c3 = 0.f, c4 = 0.f, c5 = 0.f, c6 = 0.f, c7 = 0.f;
    const unsigned short* ip = inputs_bf + (size_t)b * 40960 + lane * 8;
    for (int t = w; t < 80; t += 8) {
      float al = alpha_s[t];
      union { i32x4 v; unsigned int u[4]; } u;
      u.v = *(const i32x4*)(ip + t * 512);
      c0 = fmaf(al, bfu_lo(u.u[0]), c0); c1 = fmaf(al, bfu_hi(u.u[0]), c1);
      c2 = fmaf(al, bfu_lo(u.u[1]), c2); c3 = fmaf(al, bfu_hi(u.u[1]), c3);
      c4 = fmaf(al, bfu_lo(u.u[2]), c4); c5 = fmaf(al, bfu_hi(u.u[2]), c5);
      c6 = fmaf(al, bfu_lo(u.u[3]), c6); c7 = fmaf(al, bfu_hi(u.u[3]), c7);
    }
    f32x4 p0 = {c0, c1, c2, c3}, p1 = {c4, c5, c6, c7};
    *(f32x4*)&red[w * 512 + lane * 8] = p0;
    *(f32x4*)&red[w * 512 + lane * 8 + 4] = p1;
  }
  __syncthreads();
  {
    float sum = 0.f;
#pragma unroll
    for (int ww = 0; ww < 8; ++ww) sum += red[ww * 512 + tid];
    ctx_bf[(size_t)b * 512 + tid] = f2bf(sum);
  }
}

// ---------------- D2: [gh; gi] dual GEMM + GRU cell epilogue (R17-proven, grid 16x8) ----------------
__global__ __launch_bounds__(256) void gru_step_kernel(
    const unsigned short* __restrict__ h_in,   // [256,512]
    const unsigned short* __restrict__ ctx,    // [256,512]
    const unsigned short* __restrict__ whh,    // [1536,512]
    const unsigned short* __restrict__ wihc,   // [1536,512]
    const unsigned short* __restrict__ ohT,    // [6625,1536]
    const int* __restrict__ targets,           // [256,25]
    const float* __restrict__ bih, const float* __restrict__ bhh,
    unsigned short* __restrict__ h_out,        // [256,512]
    unsigned short* __restrict__ hid_bf,       // [6400,512]
    int s)
{
  __shared__ __align__(16) char sm[32768];
  unsigned short* lAh = (unsigned short*)sm;   // [32][64] halfwords, swizzled
  unsigned short* lAc = lAh + 2048;
  unsigned short* lBw = lAh + 4096;            // [96][64]
  unsigned short* lBi = lAh + 10240;

  const int tid = threadIdx.x;
  const int lane = tid & 63;
  const int w = tid >> 6;
  const int fr = lane & 15, kg = lane >> 4;
  const int wm = w >> 1, wn = w & 1;
  const int m0 = blockIdx.y * 32;
  const int c0 = blockIdx.x * 32;

  f32x4 ag[3], ai[3];
#pragma unroll
  for (int j = 0; j < 3; ++j) { ag[j] = 0.f; ai[j] = 0.f; }

  for (int kt = 0; kt < 8; ++kt) {
    const int kb = kt * 64;
    {
      int row = tid >> 3, k8 = tid & 7;
      int sk8 = k8 ^ (row & 7);
      stage16(h_in + (size_t)(m0 + row) * 512 + kb + sk8 * 8, lAh + (w * 64) * 8, lane);
      stage16(ctx  + (size_t)(m0 + row) * 512 + kb + sk8 * 8, lAc + (w * 64) * 8, lane);
    }
#pragma unroll
    for (int i = 0; i < 3; ++i) {
      int c = tid + i * 256;
      int br = c >> 3, k8 = c & 7;
      int sk8 = k8 ^ (br & 7);
      int gr = (br >> 5) * 512 + c0 + (br & 31);
      stage16(whh  + (size_t)gr * 512 + kb + sk8 * 8, lBw + (i * 256 + w * 64) * 8, lane);
      stage16(wihc + (size_t)gr * 512 + kb + sk8 * 8, lBi + (i * 256 + w * 64) * 8, lane);
    }
    __syncthreads();

#pragma unroll
    for (int ks = 0; ks < 2; ++ks) {
      const int kc = ks * 4 + kg;
      i32x4 ah, ac, bw[3], bi[3];
      {
        int r = wm * 16 + fr;
        int off = r * 64 + (kc ^ (r & 7)) * 8;
        ah = *(const i32x4*)&lAh[off];
        ac = *(const i32x4*)&lAc[off];
      }
#pragma unroll
      for (int j = 0; j < 3; ++j) {
        int r = wn * 48 + j * 16 + fr;
        int off = r * 64 + (kc ^ (r & 7)) * 8;
        bw[j] = *(const i32x4*)&lBw[off];
        bi[j] = *(const i32x4*)&lBi[off];
      }
#pragma unroll
      for (int j = 0; j < 3; ++j) {
        mfma_bf16_16x16x32(ag[j], ah, bw[j]);
        mfma_bf16_16x16x32(ai[j], ac, bi[j]);
      }
    }
    __syncthreads();
  }

  // epilogue: bounce acc through LDS, then GRU cell
  float* accg = (float*)sm;        // [32][96]
  float* acci = accg + 3072;
  const int crow = (lane >> 4) * 4;
  const int ccol = lane & 15;
#pragma unroll
  for (int j = 0; j < 3; ++j) {
    int col = wn * 48 + j * 16 + ccol;
#pragma unroll
    for (int r = 0; r < 4; ++r) {
      int row = wm * 16 + crow + r;
      accg[row * 96 + col] = ag[j][r];
      acci[row * 96 + col] = ai[j][r];
    }
  }
  __syncthreads();

#pragma unroll
  for (int e = tid; e < 1024; e += 256) {
    int row = e >> 5, cc = e & 31;
    int b = m0 + row, ch = c0 + cc;
    int tgt = targets[b * 25 + s];
    const unsigned short* oh = ohT + (size_t)tgt * 1536;
    float ghr = accg[row * 96 + cc]      + bhh[ch];
    float ghz = accg[row * 96 + 32 + cc] + bhh[512 + ch];
    float ghn = accg[row * 96 + 64 + cc] + bhh[1024 + ch];
    float gir = acci[row * 96 + cc]      + bih[ch]        + bf2f(oh[ch]);
    float giz = acci[row * 96 + 32 + cc] + bih[512 + ch]  + bf2f(oh[512 + ch]);
    float gin = acci[row * 96 + 64 + cc] + bih[1024 + ch] + bf2f(oh[1024 + ch]);
    float r_ = fast_sigmoid(gir + ghr);
    float z_ = fast_sigmoid(giz + ghz);
    float n_ = fast_tanh(gin + r_ * ghn);
    float h = (1.f - z_) * n_ + z_ * bf2f(h_in[(size_t)b * 512 + ch]);
    unsigned short hb = f2bf(h);
    h_out[(size_t)b * 512 + ch] = hb;
    hid_bf[((size_t)b * 25 + s) * 512 + ch] = hb;
  }
}

extern "C" void kernel_launch(void* const* d_in, const int* in_sizes, int n_in,
                              void* d_out, int out_size, void* d_ws, size_t ws_size,
                              hipStream_t stream) {
  (void)in_sizes; (void)n_in; (void)out_size; (void)ws_size;
  const float* inputs  = (const float*)d_in[0];
  const int*   targets = (const int*)d_in[1];
  const float* i2h_w   = (const float*)d_in[3];
  const float* h2h_w   = (const float*)d_in[4];
  const float* h2h_b   = (const float*)d_in[5];
  const float* score_w = (const float*)d_in[6];
  const float* gru_wih = (const float*)d_in[7];
  const float* gru_whh = (const float*)d_in[8];
  const float* gru_bih = (const float*)d_in[9];
  const float* gru_bhh = (const float*)d_in[10];
  const float* gen_w   = (const float*)d_in[11];
  const float* gen_b   = (const float*)d_in[12];
  float* out = (float*)d_out;

  char* ws = (char*)d_ws;
  size_t off = 0;
  auto alloc = [&](size_t bytes) {
    char* p = ws + off;
    off += (bytes + 255) & ~(size_t)255;
    return p;
  };
  unsigned short* inputs_bf = (unsigned short*)alloc(10485760ull * 2);
  unsigned short* proj_bf   = (unsigned short*)alloc(10485760ull * 2);
  unsigned short* i2h_bf    = (unsigned short*)alloc(262144ull * 2);
  unsigned short* h2hP_bf   = (unsigned short*)alloc(262144ull * 2);
  unsigned short* whh_bf    = (unsigned short*)alloc(786432ull * 2);
  unsigned short* wihc_bf   = (unsigned short*)alloc(786432ull * 2);
  unsigned short* ohT_bf    = (unsigned short*)alloc(10176000ull * 2);
  unsigned short* genw_bf   = (unsigned short*)alloc(3407872ull * 2);
  unsigned short* ctx_bf    = (unsigned short*)alloc(131072ull * 2);
  unsigned short* hbuf0     = (unsigned short*)alloc(131072ull * 2);
  unsigned short* hbuf1     = (unsigned short*)alloc(131072ull * 2);
  unsigned short* hid_bf    = (unsigned short*)alloc(3276800ull * 2);

  // prologue: one merged prep dispatch + proj GEMM + h zero-init
  prep_kernel<<<38656, 256, 0, stream>>>(
      inputs, i2h_w, h2h_w, gru_whh, gru_wih, gen_w,
      inputs_bf, i2h_bf, h2hP_bf, whh_bf, wihc_bf, genw_bf, ohT_bf);
  gemm_bf16out_kernel<<<dim3(4, 160), 256, 0, stream>>>(inputs_bf, i2h_bf, proj_bf, 512, 512);
  hipMemsetAsync(hbuf0, 0, 131072 * 2, stream);

  // 25 steps, 2 dispatches each; h ping-pongs between hbuf0/hbuf1
  unsigned short* hb[2] = {hbuf0, hbuf1};
  for (int s = 0; s < 25; ++s) {
    attn_step_kernel<<<256, 512, 0, stream>>>(
        proj_bf, inputs_bf, h2hP_bf, h2h_b, score_w, hb[s & 1], ctx_bf, s);
    gru_step_kernel<<<dim3(16, 8), 256, 0, stream>>>(
        hb[s & 1], ctx_bf, whh_bf, wihc_bf, ohT_bf, targets,
        gru_bih, gru_bhh, hb[(s + 1) & 1], hid_bf, s);
  }

  // epilogue: probs = hiddens @ gen_w^T + gen_b
  gemm_f32bias_kernel<<<dim3(52, 50), 256, 0, stream>>>(hid_bf, genw_bf, out, gen_b, 512, 6625, 6625);
}

// Round 19
// 891.062 us; speedup vs baseline: 1.0120x; 1.0120x over previous
//
#include <hip/hip_runtime.h>
#include <stdint.h>

typedef float f32x4 __attribute__((ext_vector_type(4)));
typedef int i32x4 __attribute__((ext_vector_type(4)));

#define LOG2E 1.4426950408889634f

__device__ __forceinline__ float bf2f(unsigned short u) {
  union { unsigned int i; float f; } x; x.i = ((unsigned int)u) << 16; return x.f;
}
__device__ __forceinline__ float bfu_lo(unsigned u) {
  union { unsigned int i; float f; } x; x.i = u << 16; return x.f;
}
__device__ __forceinline__ float bfu_hi(unsigned u) {
  union { unsigned int i; float f; } x; x.i = u & 0xffff0000u; return x.f;
}
__device__ __forceinline__ unsigned short f2bf(float f) {
  union { float f; unsigned int i; } x; x.f = f;
  unsigned int u = x.i + 0x7fffu + ((x.i >> 16) & 1u);
  return (unsigned short)(u >> 16);
}
__device__ __forceinline__ float fexp2(float x) {
#if __has_builtin(__builtin_amdgcn_exp2f)
  return __builtin_amdgcn_exp2f(x);
#else
  return exp2f(x);
#endif
}
__device__ __forceinline__ float frcp(float x) {
#if __has_builtin(__builtin_amdgcn_rcpf)
  return __builtin_amdgcn_rcpf(x);
#else
  return 1.f / x;
#endif
}
__device__ __forceinline__ float fast_exp(float x) { return fexp2(x * LOG2E); }
__device__ __forceinline__ float fast_tanh(float x) {
  float e = fexp2(x * (2.f * LOG2E));
  return 1.f - 2.f * frcp(e + 1.f);
}
__device__ __forceinline__ float fast_sigmoid(float x) {
  return frcp(1.f + fexp2(-x * LOG2E));
}

__device__ __forceinline__ void mfma_bf16_16x16x32(f32x4& d, i32x4 a, i32x4 b) {
  asm("v_mfma_f32_16x16x32_bf16 %0, %1, %2, %0" : "+v"(d) : "v"(a), "v"(b));
}

__device__ __forceinline__ void stage16(const unsigned short* g, unsigned short* lds_wave_base, int lane) {
#if __has_builtin(__builtin_amdgcn_global_load_lds)
  __builtin_amdgcn_global_load_lds(
      (const __attribute__((address_space(1))) unsigned int*)(uintptr_t)g,
      (__attribute__((address_space(3))) unsigned int*)(uintptr_t)lds_wave_base,
      16, 0, 0);
#else
  i32x4 v = *(const i32x4*)g;
  *(i32x4*)(lds_wave_base + lane * 8) = v;
#endif
}

// General bijective XCD-aware swizzle (m204 form; valid for any nwg)
__device__ __forceinline__ void xcd_swizzle(int& bx, int& by) {
  int nx = gridDim.x, nwg = nx * gridDim.y;
  int id = by * nx + bx;
  int q = nwg >> 3, r = nwg & 7;
  int x = id & 7, j = id >> 3;
  int swz = (x < r ? x * (q + 1) : r * (q + 1) + (x - r) * q) + j;
  bx = swz % nx;
  by = swz / nx;
}

// ---------------- LDS-staged GEMM (BK=64, XOR-swizzled; R12-proven) ----------------
#define BM 128
#define BN 128
#define BK 64

template <bool OUT_BF16, bool BIAS>
__device__ __forceinline__ void gemm_body(
    const unsigned short* __restrict__ A, const unsigned short* __restrict__ B,
    void* __restrict__ Cout, const float* __restrict__ bias,
    int K, int ldc, int nbound, int m0, int n0)
{
  __shared__ __align__(16) unsigned short lA[BM * BK];
  __shared__ __align__(16) unsigned short lB[BN * BK];
  const int tid = threadIdx.x;
  const int lane = tid & 63;
  const int w = tid >> 6;
  const int wm = w >> 1, wn = w & 1;
  const int fr = lane & 15;
  const int kg = lane >> 4;

  f32x4 acc[4][4];
#pragma unroll
  for (int i = 0; i < 4; ++i)
#pragma unroll
    for (int j = 0; j < 4; ++j) acc[i][j] = 0.f;

  const int nK = K / BK;
  for (int kt = 0; kt < nK; ++kt) {
    const int kb = kt * BK;
#pragma unroll
    for (int i = 0; i < 4; ++i) {
      int c = tid + i * 256;
      int row = c >> 3, k8 = c & 7;
      int sk8 = k8 ^ (row & 7);
      stage16(A + (size_t)(m0 + row) * K + kb + sk8 * 8, lA + (i * 256 + w * 64) * 8, lane);
      stage16(B + (size_t)(n0 + row) * K + kb + sk8 * 8, lB + (i * 256 + w * 64) * 8, lane);
    }
    __syncthreads();

#pragma unroll
    for (int ks = 0; ks < 2; ++ks) {
      const int kc = ks * 4 + kg;
      i32x4 af[4], bfr[4];
#pragma unroll
      for (int i = 0; i < 4; ++i) {
        int ra = wm * 64 + i * 16 + fr;
        af[i] = *(const i32x4*)&lA[ra * 64 + (kc ^ (ra & 7)) * 8];
        int rb = wn * 64 + i * 16 + fr;
        bfr[i] = *(const i32x4*)&lB[rb * 64 + (kc ^ (rb & 7)) * 8];
      }
#pragma unroll
      for (int i = 0; i < 4; ++i)
#pragma unroll
        for (int j = 0; j < 4; ++j) mfma_bf16_16x16x32(acc[i][j], af[i], bfr[j]);
    }
    __syncthreads();
  }

  const int crow = (lane >> 4) * 4;
  const int ccol = lane & 15;
#pragma unroll
  for (int i = 0; i < 4; ++i) {
#pragma unroll
    for (int j = 0; j < 4; ++j) {
      int gn = n0 + wn * 64 + j * 16 + ccol;
      if (gn < nbound) {
        float bv = BIAS ? bias[gn] : 0.f;
        int gmb = m0 + wm * 64 + i * 16 + crow;
#pragma unroll
        for (int r = 0; r < 4; ++r) {
          float v = acc[i][j][r] + bv;
          if (OUT_BF16) ((unsigned short*)Cout)[(size_t)(gmb + r) * ldc + gn] = f2bf(v);
          else          ((float*)Cout)[(size_t)(gmb + r) * ldc + gn] = v;
        }
      }
    }
  }
}

__global__ __launch_bounds__(256) void gemm_bf16out_kernel(
    const unsigned short* __restrict__ A, const unsigned short* __restrict__ B,
    unsigned short* __restrict__ C, int K, int ldc) {
  int bx = blockIdx.x, by = blockIdx.y;
  xcd_swizzle(bx, by);
  gemm_body<true, false>(A, B, C, nullptr, K, ldc, 1 << 30, by * BM, bx * BN);
}
__global__ __launch_bounds__(256) void gemm_f32bias_kernel(
    const unsigned short* __restrict__ A, const unsigned short* __restrict__ B,
    float* __restrict__ C, const float* __restrict__ bias, int K, int ldc, int nbound) {
  int bx = blockIdx.x, by = blockIdx.y;
  xcd_swizzle(bx, by);
  gemm_body<false, true>(A, B, C, bias, K, ldc, nbound, by * BM, bx * BN);
}

// ---------------- merged prep kernel (block-range dispatch; R12-proven) ----------------
__global__ __launch_bounds__(256) void prep_kernel(
    const float* __restrict__ inputs, const float* __restrict__ i2h_w,
    const float* __restrict__ h2h_w, const float* __restrict__ gru_whh,
    const float* __restrict__ gru_wih, const float* __restrict__ gen_w,
    unsigned short* __restrict__ inputs_bf, unsigned short* __restrict__ i2h_bf,
    unsigned short* __restrict__ h2hP, unsigned short* __restrict__ whh_bf,
    unsigned short* __restrict__ wihc_bf, unsigned short* __restrict__ genw_bf,
    unsigned short* __restrict__ ohT_bf)
{
  __shared__ float tile[32][33];
  const int blk = blockIdx.x;
  const int t = threadIdx.x;

  if (blk < 10240) {
    int i = blk * 256 + t;
    float4 v = ((const float4*)inputs)[i];
    ushort4 o; o.x = f2bf(v.x); o.y = f2bf(v.y); o.z = f2bf(v.z); o.w = f2bf(v.w);
    ((ushort4*)inputs_bf)[i] = o;
  } else if (blk < 10496) {
    int i = (blk - 10240) * 256 + t;
    float4 v = ((const float4*)i2h_w)[i];
    ushort4 o; o.x = f2bf(v.x); o.y = f2bf(v.y); o.z = f2bf(v.z); o.w = f2bf(v.w);
    ((ushort4*)i2h_bf)[i] = o;
  } else if (blk < 11520) {
    int i = (blk - 10496) * 256 + t;            // h2hP[kb][row][kk] = h2h_w[row][kb*8+kk]
    int row = i >> 9, c = i & 511;
    int kb = c >> 3, kk = c & 7;
    h2hP[((size_t)kb * 512 + row) * 8 + kk] = f2bf(h2h_w[i]);
  } else if (blk < 12288) {
    int i = (blk - 11520) * 256 + t;
    float4 v = ((const float4*)gru_whh)[i];
    ushort4 o; o.x = f2bf(v.x); o.y = f2bf(v.y); o.z = f2bf(v.z); o.w = f2bf(v.w);
    ((ushort4*)whh_bf)[i] = o;
  } else if (blk < 15360) {
    int i = (blk - 12288) * 256 + t;            // wihc = gru_wih[:, :512]
    int j = i >> 9, c = i & 511;
    wihc_bf[i] = f2bf(gru_wih[(size_t)j * 7137 + c]);
  } else if (blk < 28672) {
    int i = (blk - 15360) * 256 + t;            // genw padded [6656,512]
    int nrow = i >> 9, c = i & 511;
    float v = (nrow < 6625) ? gen_w[(size_t)nrow * 512 + c] : 0.f;
    genw_bf[i] = f2bf(v);
  } else {
    int tb = blk - 28672;                       // ohT[t,j] = gru_wih[j, 512+t]
    int t0 = (tb % 208) * 32;
    int j0 = (tb / 208) * 32;
    int c = t & 31;
    int r4 = t >> 5;
#pragma unroll
    for (int rr = 0; rr < 4; ++rr) {
      int r = r4 + rr * 8;
      int tcol = t0 + c;
      tile[r][c] = (tcol < 6625) ? gru_wih[(size_t)(j0 + r) * 7137 + 512 + tcol] : 0.f;
    }
    __syncthreads();
#pragma unroll
    for (int rr = 0; rr < 4; ++rr) {
      int r = r4 + rr * 8;
      int trow = t0 + r;
      if (trow < 6625) ohT_bf[(size_t)trow * 1536 + j0 + c] = f2bf(tile[c][r]);
    }
  }
}

// ---------------- D1: pp (per-thread dot, packed-coalesced weights) + attention + ctx ----------------
__global__ __launch_bounds__(512) void attn_step_kernel(
    const unsigned short* __restrict__ proj_bf,   // [20480, 512]
    const unsigned short* __restrict__ inputs_bf, // [20480, 512]
    const unsigned short* __restrict__ h2hP,      // [64][512][8] packed
    const float* __restrict__ h2h_b,              // [512]
    const float* __restrict__ score_w,            // [512]
    const unsigned short* __restrict__ h_in,      // [256, 512] (ignored when s==0)
    unsigned short* __restrict__ ctx_bf,          // [256, 512]
    int s)
{
  __shared__ float h_lds[512];
  __shared__ float pp_lds[512];
  __shared__ float e_s[80];
  __shared__ float alpha_s[80];

  const int tid = threadIdx.x;
  const int lane = tid & 63;
  const int w = tid >> 6;
  const int b = blockIdx.x;

  if (s > 0) h_lds[tid] = bf2f(h_in[b * 512 + tid]);
  __syncthreads();

  float pacc = h2h_b[tid];
  if (s > 0) {
    const unsigned short* wp = h2hP + (size_t)tid * 8;
#pragma unroll 4
    for (int kb = 0; kb < 64; ++kb) {
      union { i32x4 v; unsigned int u[4]; } wu;
      wu.v = *(const i32x4*)(wp + (size_t)kb * 4096);
#pragma unroll
      for (int q = 0; q < 4; ++q) {
        pacc = fmaf(bfu_lo(wu.u[q]), h_lds[kb * 8 + 2 * q], pacc);
        pacc = fmaf(bfu_hi(wu.u[q]), h_lds[kb * 8 + 2 * q + 1], pacc);
      }
    }
  }
  pp_lds[tid] = pacc;
  __syncthreads();

  // scores
  float ppv[8], swv[8];
#pragma unroll
  for (int j = 0; j < 8; ++j) ppv[j] = pp_lds[lane * 8 + j];
  *(float4*)&swv[0] = *(const float4*)(score_w + lane * 8);
  *(float4*)&swv[4] = *(const float4*)(score_w + lane * 8 + 4);

  for (int t = w; t < 80; t += 8) {
    union { i32x4 v; unsigned int u[4]; } u;
    u.v = *(const i32x4*)(proj_bf + (size_t)(b * 80 + t) * 512 + lane * 8);
    float acc = 0.f;
#pragma unroll
    for (int q = 0; q < 4; ++q) {
      acc += fast_tanh(bfu_lo(u.u[q]) + ppv[2 * q]) * swv[2 * q];
      acc += fast_tanh(bfu_hi(u.u[q]) + ppv[2 * q + 1]) * swv[2 * q + 1];
    }
#pragma unroll
    for (int m = 32; m >= 1; m >>= 1) acc += __shfl_xor(acc, m, 64);
    if (lane == 0) e_s[t] = acc;
  }
  __syncthreads();
  if (w == 0) {
    float v0 = e_s[lane];
    float v1 = (lane < 16) ? e_s[64 + lane] : -1e30f;
    float mx = fmaxf(v0, v1);
#pragma unroll
    for (int m = 32; m >= 1; m >>= 1) mx = fmaxf(mx, __shfl_xor(mx, m, 64));
    float a0 = fast_exp(v0 - mx);
    float a1 = (lane < 16) ? fast_exp(v1 - mx) : 0.f;
    float sm = a0 + a1;
#pragma unroll
    for (int m = 32; m >= 1; m >>= 1) sm += __shfl_xor(sm, m, 64);
    float inv = frcp(sm);
    alpha_s[lane] = a0 * inv;
    if (lane < 16) alpha_s[64 + lane] = a1 * inv;
  }
  __syncthreads();

  // ctx[b][tid]
  float cacc = 0.f;
  const unsigned short* ip = inputs_bf + (size_t)b * 40960;
#pragma unroll 8
  for (int t = 0; t < 80; ++t)
    cacc = fmaf(alpha_s[t], bf2f(ip[t * 512 + tid]), cacc);
  ctx_bf[(size_t)b * 512 + tid] = f2bf(cacc);
}

// ---------------- D2: [gh; gi] dual GEMM + GRU cell epilogue (grid 16x8; R17-proven) ----------------
__global__ __launch_bounds__(256) void gru_step_kernel(
    const unsigned short* __restrict__ h_in,   // [256,512]
    const unsigned short* __restrict__ ctx,    // [256,512]
    const unsigned short* __restrict__ whh,    // [1536,512]
    const unsigned short* __restrict__ wihc,   // [1536,512]
    const unsigned short* __restrict__ ohT,    // [6625,1536]
    const int* __restrict__ targets,           // [256,25]
    const float* __restrict__ bih, const float* __restrict__ bhh,
    unsigned short* __restrict__ h_out,        // [256,512]
    unsigned short* __restrict__ hid_bf,       // [6400,512]
    int s)
{
  __shared__ __align__(16) char sm[32768];
  unsigned short* lAh = (unsigned short*)sm;   // [32][64] halfwords, swizzled
  unsigned short* lAc = lAh + 2048;
  unsigned short* lBw = lAh + 4096;            // [96][64]
  unsigned short* lBi = lAh + 10240;

  const int tid = threadIdx.x;
  const int lane = tid & 63;
  const int w = tid >> 6;
  const int fr = lane & 15, kg = lane >> 4;
  const int wm = w >> 1, wn = w & 1;
  const int m0 = blockIdx.y * 32;
  const int c0 = blockIdx.x * 32;

  f32x4 ag[3], ai[3];
#pragma unroll
  for (int j = 0; j < 3; ++j) { ag[j] = 0.f; ai[j] = 0.f; }

  for (int kt = 0; kt < 8; ++kt) {
    const int kb = kt * 64;
    {
      int row = tid >> 3, k8 = tid & 7;
      int sk8 = k8 ^ (row & 7);
      stage16(h_in + (size_t)(m0 + row) * 512 + kb + sk8 * 8, lAh + (w * 64) * 8, lane);
      stage16(ctx  + (size_t)(m0 + row) * 512 + kb + sk8 * 8, lAc + (w * 64) * 8, lane);
    }
#pragma unroll
    for (int i = 0; i < 3; ++i) {
      int c = tid + i * 256;
      int br = c >> 3, k8 = c & 7;
      int sk8 = k8 ^ (br & 7);
      int gr = (br >> 5) * 512 + c0 + (br & 31);
      stage16(whh  + (size_t)gr * 512 + kb + sk8 * 8, lBw + (i * 256 + w * 64) * 8, lane);
      stage16(wihc + (size_t)gr * 512 + kb + sk8 * 8, lBi + (i * 256 + w * 64) * 8, lane);
    }
    __syncthreads();

#pragma unroll
    for (int ks = 0; ks < 2; ++ks) {
      const int kc = ks * 4 + kg;
      i32x4 ah, ac, bw[3], bi[3];
      {
        int r = wm * 16 + fr;
        int off = r * 64 + (kc ^ (r & 7)) * 8;
        ah = *(const i32x4*)&lAh[off];
        ac = *(const i32x4*)&lAc[off];
      }
#pragma unroll
      for (int j = 0; j < 3; ++j) {
        int r = wn * 48 + j * 16 + fr;
        int off = r * 64 + (kc ^ (r & 7)) * 8;
        bw[j] = *(const i32x4*)&lBw[off];
        bi[j] = *(const i32x4*)&lBi[off];
      }
#pragma unroll
      for (int j = 0; j < 3; ++j) {
        mfma_bf16_16x16x32(ag[j], ah, bw[j]);
        mfma_bf16_16x16x32(ai[j], ac, bi[j]);
      }
    }
    __syncthreads();
  }

  // epilogue: bounce acc through LDS, then GRU cell
  float* accg = (float*)sm;        // [32][96]
  float* acci = accg + 3072;
  const int crow = (lane >> 4) * 4;
  const int ccol = lane & 15;
#pragma unroll
  for (int j = 0; j < 3; ++j) {
    int col = wn * 48 + j * 16 + ccol;
#pragma unroll
    for (int r = 0; r < 4; ++r) {
      int row = wm * 16 + crow + r;
      accg[row * 96 + col] = ag[j][r];
      acci[row * 96 + col] = ai[j][r];
    }
  }
  __syncthreads();

#pragma unroll
  for (int e = tid; e < 1024; e += 256) {
    int row = e >> 5, cc = e & 31;
    int b = m0 + row, ch = c0 + cc;
    int tgt = targets[b * 25 + s];
    const unsigned short* oh = ohT + (size_t)tgt * 1536;
    float ghr = accg[row * 96 + cc]      + bhh[ch];
    float ghz = accg[row * 96 + 32 + cc] + bhh[512 + ch];
    float ghn = accg[row * 96 + 64 + cc] + bhh[1024 + ch];
    float gir = acci[row * 96 + cc]      + bih[ch]        + bf2f(oh[ch]);
    float giz = acci[row * 96 + 32 + cc] + bih[512 + ch]  + bf2f(oh[512 + ch]);
    float gin = acci[row * 96 + 64 + cc] + bih[1024 + ch] + bf2f(oh[1024 + ch]);
    float r_ = fast_sigmoid(gir + ghr);
    float z_ = fast_sigmoid(giz + ghz);
    float n_ = fast_tanh(gin + r_ * ghn);
    float h = (1.f - z_) * n_ + z_ * bf2f(h_in[(size_t)b * 512 + ch]);
    unsigned short hb = f2bf(h);
    h_out[(size_t)b * 512 + ch] = hb;
    hid_bf[((size_t)b * 25 + s) * 512 + ch] = hb;
  }
}

extern "C" void kernel_launch(void* const* d_in, const int* in_sizes, int n_in,
                              void* d_out, int out_size, void* d_ws, size_t ws_size,
                              hipStream_t stream) {
  (void)in_sizes; (void)n_in; (void)out_size; (void)ws_size;
  const float* inputs  = (const float*)d_in[0];
  const int*   targets = (const int*)d_in[1];
  const float* i2h_w   = (const float*)d_in[3];
  const float* h2h_w   = (const float*)d_in[4];
  const float* h2h_b   = (const float*)d_in[5];
  const float* score_w = (const float*)d_in[6];
  const float* gru_wih = (const float*)d_in[7];
  const float* gru_whh = (const float*)d_in[8];
  const float* gru_bih = (const float*)d_in[9];
  const float* gru_bhh = (const float*)d_in[10];
  const float* gen_w   = (const float*)d_in[11];
  const float* gen_b   = (const float*)d_in[12];
  float* out = (float*)d_out;

  char* ws = (char*)d_ws;
  size_t off = 0;
  auto alloc = [&](size_t bytes) {
    char* p = ws + off;
    off += (bytes + 255) & ~(size_t)255;
    return p;
  };
  unsigned short* inputs_bf = (unsigned short*)alloc(10485760ull * 2);
  unsigned short* proj_bf   = (unsigned short*)alloc(10485760ull * 2);
  unsigned short* i2h_bf    = (unsigned short*)alloc(262144ull * 2);
  unsigned short* h2hP_bf   = (unsigned short*)alloc(262144ull * 2);
  unsigned short* whh_bf    = (unsigned short*)alloc(786432ull * 2);
  unsigned short* wihc_bf   = (unsigned short*)alloc(786432ull * 2);
  unsigned short* ohT_bf    = (unsigned short*)alloc(10176000ull * 2);
  unsigned short* genw_bf   = (unsigned short*)alloc(3407872ull * 2);
  unsigned short* ctx_bf    = (unsigned short*)alloc(131072ull * 2);
  unsigned short* hbuf0     = (unsigned short*)alloc(131072ull * 2);
  unsigned short* hbuf1     = (unsigned short*)alloc(131072ull * 2);
  unsigned short* hid_bf    = (unsigned short*)alloc(3276800ull * 2);

  // prologue: one merged prep dispatch + proj GEMM + h zero-init
  prep_kernel<<<38656, 256, 0, stream>>>(
      inputs, i2h_w, h2h_w, gru_whh, gru_wih, gen_w,
      inputs_bf, i2h_bf, h2hP_bf, whh_bf, wihc_bf, genw_bf, ohT_bf);
  gemm_bf16out_kernel<<<dim3(4, 160), 256, 0, stream>>>(inputs_bf, i2h_bf, proj_bf, 512, 512);
  hipMemsetAsync(hbuf0, 0, 131072 * 2, stream);

  // 25 steps, 2 dispatches each; h ping-pongs between hbuf0/hbuf1
  unsigned short* hb[2] = {hbuf0, hbuf1};
  for (int s = 0; s < 25; ++s) {
    attn_step_kernel<<<256, 512, 0, stream>>>(
        proj_bf, inputs_bf, h2hP_bf, h2h_b, score_w, hb[s & 1], ctx_bf, s);
    gru_step_kernel<<<dim3(16, 8), 256, 0, stream>>>(
        hb[s & 1], ctx_bf, whh_bf, wihc_bf, ohT_bf, targets,
        gru_bih, gru_bhh, hb[(s + 1) & 1], hid_bf, s);
  }

  // epilogue: probs = hiddens @ gen_w^T + gen_b
  gemm_f32bias_kernel<<<dim3(52, 50), 256, 0, stream>>>(hid_bf, genw_bf, out, gen_b, 512, 6625, 6625);
}